// Round 2
// baseline (1168.898 us; speedup 1.0000x reference)
//
#include <hip/hip_runtime.h>
#include <hip/hip_bf16.h>

// DecoderBlock: B=128, T=S=256, C=384, H=6, D=64. fp32 in/out, bf16 MFMA compute.
#define BB 128
#define TT 256
#define CC 384
#define HH 6
#define DD 64
#define NTOK 32768  // B*T

typedef __attribute__((ext_vector_type(8))) short short8;
typedef __attribute__((ext_vector_type(4))) float f32x4;

__device__ __forceinline__ unsigned short f2bf(float f) {
  union { float f; unsigned int u; } v; v.f = f;
  unsigned int r = v.u + 0x7fff + ((v.u >> 16) & 1);  // RNE
  return (unsigned short)(r >> 16);
}

// ---------------- weight packing ----------------
// dst[(h*D+d)*C + c] = w[h][c][d]   (head-stacked -> B^T rows j=h*64+d)
__global__ __launch_bounds__(256) void pack_headstack_k(const float* __restrict__ w,
                                                        unsigned short* __restrict__ dst) {
  int idx = blockIdx.x * 256 + threadIdx.x;  // over H*C*D = 147456
  int h = idx / (CC * DD);
  int rem = idx - h * (CC * DD);
  int c = rem / DD, d = rem - c * DD;
  dst[(size_t)(h * DD + d) * CC + c] = f2bf(w[idx]);
}

// dst[n*C + c] = w[c*N + n]  (plain transpose to B^T)
__global__ __launch_bounds__(256) void pack_transpose_k(const float* __restrict__ w,
                                                        unsigned short* __restrict__ dst,
                                                        int Cdim, int Ndim) {
  int idx = blockIdx.x * 256 + threadIdx.x;  // over C*N
  int c = idx / Ndim, n = idx - c * Ndim;
  dst[(size_t)n * Cdim + c] = f2bf(w[idx]);
}

// ---------------- layernorm (fp32 in -> bf16 out) ----------------
__global__ __launch_bounds__(256) void ln_k(const float* __restrict__ x,
                                            unsigned short* __restrict__ out,
                                            const float* __restrict__ gamma,
                                            const float* __restrict__ beta) {
  int row = blockIdx.x * 4 + (threadIdx.x >> 6);
  int lane = threadIdx.x & 63;
  const float* xr = x + (size_t)row * CC;
  float v[6];
  float s = 0.f;
#pragma unroll
  for (int j = 0; j < 6; ++j) { v[j] = xr[j * 64 + lane]; s += v[j]; }
#pragma unroll
  for (int m = 1; m < 64; m <<= 1) s += __shfl_xor(s, m);
  float mu = s * (1.0f / CC);
  float vs = 0.f;
#pragma unroll
  for (int j = 0; j < 6; ++j) { float d = v[j] - mu; vs += d * d; }
#pragma unroll
  for (int m = 1; m < 64; m <<= 1) vs += __shfl_xor(vs, m);
  float rs = rsqrtf(vs * (1.0f / CC) + 1e-5f);
  unsigned short* orow = out + (size_t)row * CC;
#pragma unroll
  for (int j = 0; j < 6; ++j) {
    int cidx = j * 64 + lane;
    orow[cidx] = f2bf((v[j] - mu) * rs * gamma[cidx] + beta[cidx]);
  }
}

// ---------------- GEMM: C(MxN) = A(MxK) * Bt(NxK)^T ----------------
// 128x128 tile, 4 waves (each 64x64), XOR-swizzled LDS, XCD-aware 1D grid.
// EPI 0: C=bf16 acc ; EPI 2: C=fp32 res+acc+bias
template <int EPI, bool AF32>
__global__ __launch_bounds__(256) void gemm_k(const void* __restrict__ Ap, int lda,
                                              const unsigned short* __restrict__ Bt, int ldb,
                                              void* __restrict__ Cp, int ldc,
                                              const float* __restrict__ bias,
                                              const float* __restrict__ res, int ldres,
                                              int K, int nx) {
  __shared__ unsigned short sA[128 * 64];
  __shared__ unsigned short sB[128 * 64];
  const int tid = threadIdx.x;
  // XCD-aware bijective swizzle (gridDim.x % 8 == 0 for all our grids)
  const int chunk = gridDim.x >> 3;
  const int wg = blockIdx.x;
  const int lg = (wg & 7) * chunk + (wg >> 3);
  const int bx = lg % nx, by = lg / nx;
  const int m0 = by * 128;
  const int n0 = bx * 128;
  const int wid = tid >> 6, lane = tid & 63;
  const int wr = wid >> 1, wc = wid & 1;
  const int g = lane >> 4, c = lane & 15;

  f32x4 acc[4][4] = {};

  for (int k0 = 0; k0 < K; k0 += 64) {
#pragma unroll
    for (int t = 0; t < 4; ++t) {
      int e = (t * 256 + tid);           // uint4 index over 1024
      int row = e >> 3, colgrp = e & 7;  // 128 rows x 8 groups
      int dst = row * 64 + ((colgrp ^ (row & 7)) << 3);
      if (!AF32) {
        const unsigned short* Ab = (const unsigned short*)Ap;
        *(uint4*)&sA[dst] = *(const uint4*)&Ab[(size_t)(m0 + row) * lda + k0 + colgrp * 8];
      } else {
        const float* Af = (const float*)Ap + (size_t)(m0 + row) * lda + k0 + colgrp * 8;
        float4 f0 = *(const float4*)Af;
        float4 f1 = *(const float4*)(Af + 4);
        union { unsigned short h[8]; uint4 u; } t2;
        t2.h[0] = f2bf(f0.x); t2.h[1] = f2bf(f0.y); t2.h[2] = f2bf(f0.z); t2.h[3] = f2bf(f0.w);
        t2.h[4] = f2bf(f1.x); t2.h[5] = f2bf(f1.y); t2.h[6] = f2bf(f1.z); t2.h[7] = f2bf(f1.w);
        *(uint4*)&sA[dst] = t2.u;
      }
    }
#pragma unroll
    for (int t = 0; t < 4; ++t) {
      int e = (t * 256 + tid);
      int row = e >> 3, colgrp = e & 7;
      int dst = row * 64 + ((colgrp ^ (row & 7)) << 3);
      *(uint4*)&sB[dst] = *(const uint4*)&Bt[(size_t)(n0 + row) * ldb + k0 + colgrp * 8];
    }
    __syncthreads();
#pragma unroll
    for (int kk = 0; kk < 2; ++kk) {
      short8 a[4], b[4];
#pragma unroll
      for (int mi = 0; mi < 4; ++mi) {
        int r = wr * 64 + mi * 16 + c;
        a[mi] = *(const short8*)&sA[r * 64 + (((kk * 4 + g) ^ (r & 7)) << 3)];
      }
#pragma unroll
      for (int ni = 0; ni < 4; ++ni) {
        int rb = wc * 64 + ni * 16 + c;
        b[ni] = *(const short8*)&sB[rb * 64 + (((kk * 4 + g) ^ (rb & 7)) << 3)];
      }
#pragma unroll
      for (int mi = 0; mi < 4; ++mi)
#pragma unroll
        for (int ni = 0; ni < 4; ++ni)
          acc[mi][ni] = __builtin_amdgcn_mfma_f32_16x16x32_bf16(a[mi], b[ni], acc[mi][ni], 0, 0, 0);
    }
    __syncthreads();
  }

#pragma unroll
  for (int mi = 0; mi < 4; ++mi) {
#pragma unroll
    for (int ni = 0; ni < 4; ++ni) {
#pragma unroll
      for (int i = 0; i < 4; ++i) {
        int row = m0 + wr * 64 + mi * 16 + g * 4 + i;
        int col = n0 + wc * 64 + ni * 16 + c;
        float v = acc[mi][ni][i];
        if (EPI == 0) {
          ((unsigned short*)Cp)[(size_t)row * ldc + col] = f2bf(v);
        } else {
          v += bias[col] + res[(size_t)row * ldres + col];
          ((float*)Cp)[(size_t)row * ldc + col] = v;
        }
      }
    }
  }
}

// ---------------- fused FFN: out = res + relu(xn@W1+b1)@W2 + b2 ----------------
// Per block: 64 rows, 4 waves (16 rows each). xn A-frags in registers.
// Loop 24 chunks of 64 hidden cols: htile via per-wave swizzled LDS.
__global__ __launch_bounds__(256, 2) void ffn_k(const unsigned short* __restrict__ xn,
                                                const unsigned short* __restrict__ W1t,  // [1536][384]
                                                const unsigned short* __restrict__ W2t,  // [384][1536]
                                                const float* __restrict__ b1,
                                                const float* __restrict__ b2,
                                                const float* __restrict__ res,
                                                float* __restrict__ out) {
  __shared__ unsigned short ht[4][16 * 64];
  const int tid = threadIdx.x, w = tid >> 6, lane = tid & 63;
  const int g = lane >> 4, c = lane & 15;
  const int r0 = blockIdx.x * 64 + w * 16;

  short8 a[12];
  const unsigned short* arow = xn + (size_t)(r0 + c) * 384 + g * 8;
#pragma unroll
  for (int kf = 0; kf < 12; ++kf) a[kf] = *(const short8*)&arow[kf * 32];

  f32x4 acc[24] = {};
  unsigned short* hw = ht[w];

  for (int kh = 0; kh < 24; ++kh) {
    f32x4 h[4] = {};
#pragma unroll
    for (int kf = 0; kf < 12; ++kf) {
#pragma unroll
      for (int nf = 0; nf < 4; ++nf) {
        short8 b = *(const short8*)&W1t[(size_t)(kh * 64 + nf * 16 + c) * 384 + kf * 32 + g * 8];
        h[nf] = __builtin_amdgcn_mfma_f32_16x16x32_bf16(a[kf], b, h[nf], 0, 0, 0);
      }
    }
    // relu + bias -> per-wave swizzled LDS htile [16][64]
#pragma unroll
    for (int nf = 0; nf < 4; ++nf)
#pragma unroll
      for (int i = 0; i < 4; ++i) {
        int rw = g * 4 + i;
        float v = h[nf][i] + b1[kh * 64 + nf * 16 + c];
        int colgrp = nf * 2 + (c >> 3);
        hw[rw * 64 + ((colgrp ^ (rw & 7)) << 3) + (c & 7)] = f2bf(fmaxf(v, 0.f));
      }
    // phase 2: acc += htile @ W2chunk   (same-wave LDS RAW; compiler inserts waits)
#pragma unroll
    for (int ks = 0; ks < 2; ++ks) {
      short8 pa = *(const short8*)&hw[c * 64 + (((ks * 4 + g) ^ (c & 7)) << 3)];
#pragma unroll
      for (int nf2 = 0; nf2 < 24; ++nf2) {
        short8 b = *(const short8*)&W2t[(size_t)(nf2 * 16 + c) * 1536 + kh * 64 + ks * 32 + g * 8];
        acc[nf2] = __builtin_amdgcn_mfma_f32_16x16x32_bf16(pa, b, acc[nf2], 0, 0, 0);
      }
    }
  }

#pragma unroll
  for (int nf2 = 0; nf2 < 24; ++nf2)
#pragma unroll
    for (int i = 0; i < 4; ++i) {
      int row = r0 + g * 4 + i;
      int col = nf2 * 16 + c;
      out[(size_t)row * 384 + col] = acc[nf2][i] + b2[col] + res[(size_t)row * 384 + col];
    }
}

// ---------------- attention (per (b,h) block) ----------------
__global__ __launch_bounds__(256) void attn_k(const unsigned short* __restrict__ QKV,
                                              unsigned short* __restrict__ O,
                                              int causal) {
  __shared__ unsigned short Ks[256 * 64];      // [s][d]
  __shared__ unsigned short Vt[64 * 256];      // [d][s]
  __shared__ unsigned short Ps[4 * 16 * 256];  // per-wave [16 q][256 s]
  const int bh = blockIdx.x;
  const int b = bh / HH, hh = bh - b * HH;
  const int tid = threadIdx.x, wid = tid >> 6, lane = tid & 63;
  const int g = lane >> 4, c = lane & 15;
  const unsigned short* base = QKV + (size_t)b * TT * 1152;

#pragma unroll
  for (int t = 0; t < 8; ++t) {
    int idx = (t * 256 + tid) * 8;  // 16384 elems
    int s = idx >> 6, d = idx & 63;
    *(uint4*)&Ks[idx] = *(const uint4*)&base[(size_t)s * 1152 + 384 + hh * 64 + d];
    union { unsigned short h[8]; uint4 u; } tv;
    tv.u = *(const uint4*)&base[(size_t)s * 1152 + 768 + hh * 64 + d];
#pragma unroll
    for (int j = 0; j < 8; ++j) Vt[(d + j) * 256 + s] = tv.h[j];
  }
  __syncthreads();

  const float scale = 0.05103103630798287f;  // 384^-0.5
  unsigned short* Pw = &Ps[wid * 4096];

  for (int qb = 0; qb < 4; ++qb) {
    const int qr0 = wid * 64 + qb * 16;
    short8 aq[2];
#pragma unroll
    for (int kk = 0; kk < 2; ++kk)
      aq[kk] = *(const short8*)&QKV[(size_t)(b * TT + qr0 + c) * 1152 + hh * 64 + kk * 32 + g * 8];

    f32x4 sacc[16];
#pragma unroll
    for (int sj = 0; sj < 16; ++sj) {
      f32x4 z = {};
      z = __builtin_amdgcn_mfma_f32_16x16x32_bf16(aq[0], *(const short8*)&Ks[(sj * 16 + c) * 64 + g * 8], z, 0, 0, 0);
      z = __builtin_amdgcn_mfma_f32_16x16x32_bf16(aq[1], *(const short8*)&Ks[(sj * 16 + c) * 64 + 32 + g * 8], z, 0, 0, 0);
      sacc[sj] = z;
    }

#pragma unroll
    for (int i = 0; i < 4; ++i) {
      const int qr = qr0 + g * 4 + i;
      float mx = -1e30f;
#pragma unroll
      for (int sj = 0; sj < 16; ++sj) {
        int s = sj * 16 + c;
        float v = sacc[sj][i] * scale;
        if (causal && s > qr) v = -1e30f;
        sacc[sj][i] = v;
        mx = fmaxf(mx, v);
      }
#pragma unroll
      for (int m = 1; m < 16; m <<= 1) mx = fmaxf(mx, __shfl_xor(mx, m));
      float sum = 0.f;
#pragma unroll
      for (int sj = 0; sj < 16; ++sj) {
        float p = __expf(sacc[sj][i] - mx);
        sacc[sj][i] = p;
        sum += p;
      }
#pragma unroll
      for (int m = 1; m < 16; m <<= 1) sum += __shfl_xor(sum, m);
      float inv = 1.0f / sum;
#pragma unroll
      for (int sj = 0; sj < 16; ++sj)
        Pw[(g * 4 + i) * 256 + sj * 16 + c] = f2bf(sacc[sj][i] * inv);
    }

    f32x4 oacc[4] = {};
#pragma unroll
    for (int sk = 0; sk < 8; ++sk) {
      short8 ap = *(const short8*)&Pw[c * 256 + sk * 32 + g * 8];
#pragma unroll
      for (int dj = 0; dj < 4; ++dj) {
        short8 bv = *(const short8*)&Vt[(dj * 16 + c) * 256 + sk * 32 + g * 8];
        oacc[dj] = __builtin_amdgcn_mfma_f32_16x16x32_bf16(ap, bv, oacc[dj], 0, 0, 0);
      }
    }
#pragma unroll
    for (int dj = 0; dj < 4; ++dj)
#pragma unroll
      for (int i = 0; i < 4; ++i) {
        int qr = qr0 + g * 4 + i;
        O[(size_t)(b * TT + qr) * CC + hh * 64 + dj * 16 + c] = f2bf(oacc[dj][i]);
      }
  }
}

// ---------------- launcher ----------------
extern "C" void kernel_launch(void* const* d_in, const int* in_sizes, int n_in,
                              void* d_out, int out_size, void* d_ws, size_t ws_size,
                              hipStream_t stream) {
  const float* x = (const float*)d_in[0];
  const float* enc = (const float*)d_in[1];
  const float* wq1 = (const float*)d_in[2];
  const float* wk1 = (const float*)d_in[3];
  const float* wv1 = (const float*)d_in[4];
  const float* proj1_w = (const float*)d_in[5];
  const float* proj1_b = (const float*)d_in[6];
  const float* wq2 = (const float*)d_in[7];
  const float* wk2 = (const float*)d_in[8];
  const float* wv2 = (const float*)d_in[9];
  const float* proj2_w = (const float*)d_in[10];
  const float* proj2_b = (const float*)d_in[11];
  const float* ffn_w1 = (const float*)d_in[12];
  const float* ffn_b1 = (const float*)d_in[13];
  const float* ffn_w2 = (const float*)d_in[14];
  const float* ffn_b2 = (const float*)d_in[15];
  const float* ln1_g = (const float*)d_in[16];
  const float* ln1_b = (const float*)d_in[17];
  const float* ln2_g = (const float*)d_in[18];
  const float* ln2_b = (const float*)d_in[19];
  const float* ln3_g = (const float*)d_in[20];
  const float* ln3_b = (const float*)d_in[21];
  float* out = (float*)d_out;

  char* ws = (char*)d_ws;
  const size_t OFF_A = 0;           // x_cur fp32 (B*T,384)        50331648
  const size_t OFF_X = 50331648;    // xn bf16 (B*T,384)           25165824
  const size_t OFF_Q = 75497472;    // QKV bf16 (B*T,1152)
  const size_t OFF_O = 150994944;   // O bf16 (B*T,384)            25165824
  const size_t OFF_W = 176160768;   // packed weights bf16          4718592

  float* xc = (float*)(ws + OFF_A);
  unsigned short* xn = (unsigned short*)(ws + OFF_X);
  unsigned short* qkv = (unsigned short*)(ws + OFF_Q);
  unsigned short* obuf = (unsigned short*)(ws + OFF_O);
  unsigned short* W = (unsigned short*)(ws + OFF_W);

  unsigned short* Wqkv1t = W + 0;        // 1152x384
  unsigned short* Wq2t = W + 442368;     // 384x384
  unsigned short* Wkv2t = W + 589824;    // 768x384
  unsigned short* proj1t = W + 884736;   // 384x384
  unsigned short* proj2t = W + 1032192;  // 384x384
  unsigned short* W1t = W + 1179648;     // 1536x384
  unsigned short* W2t = W + 1769472;     // 384x1536

  // ---- pack weights ----
  pack_headstack_k<<<576, 256, 0, stream>>>(wq1, Wqkv1t);
  pack_headstack_k<<<576, 256, 0, stream>>>(wk1, Wqkv1t + 147456);
  pack_headstack_k<<<576, 256, 0, stream>>>(wv1, Wqkv1t + 294912);
  pack_headstack_k<<<576, 256, 0, stream>>>(wq2, Wq2t);
  pack_headstack_k<<<576, 256, 0, stream>>>(wk2, Wkv2t);
  pack_headstack_k<<<576, 256, 0, stream>>>(wv2, Wkv2t + 147456);
  pack_transpose_k<<<576, 256, 0, stream>>>(proj1_w, proj1t, 384, 384);
  pack_transpose_k<<<576, 256, 0, stream>>>(proj2_w, proj2t, 384, 384);
  pack_transpose_k<<<2304, 256, 0, stream>>>(ffn_w1, W1t, 384, 1536);
  pack_transpose_k<<<2304, 256, 0, stream>>>(ffn_w2, W2t, 1536, 384);

  dim3 blk(256);
  // ---- layer 1: masked self-attention ----
  ln_k<<<8192, blk, 0, stream>>>(x, xn, ln1_g, ln1_b);
  gemm_k<0, false><<<2304, blk, 0, stream>>>(xn, 384, Wqkv1t, 384, qkv, 1152,
                                             nullptr, nullptr, 0, 384, 9);
  attn_k<<<768, blk, 0, stream>>>(qkv, obuf, 1);
  gemm_k<2, false><<<768, blk, 0, stream>>>(obuf, 384, proj1t, 384, xc, 384,
                                            proj1_b, x, 384, 384, 3);
  // ---- layer 2: cross-attention ----
  ln_k<<<8192, blk, 0, stream>>>(xc, xn, ln2_g, ln2_b);
  gemm_k<0, false><<<768, blk, 0, stream>>>(xn, 384, Wq2t, 384, qkv, 1152,
                                            nullptr, nullptr, 0, 384, 3);
  gemm_k<0, true><<<1536, blk, 0, stream>>>(enc, 384, Wkv2t, 384, qkv + 384, 1152,
                                            nullptr, nullptr, 0, 384, 6);
  attn_k<<<768, blk, 0, stream>>>(qkv, obuf, 0);
  gemm_k<2, false><<<768, blk, 0, stream>>>(obuf, 384, proj2t, 384, xc, 384,
                                            proj2_b, xc, 384, 384, 3);
  // ---- FFN (fused LN3 stays separate; FFN1+relu+FFN2+residual fused) ----
  ln_k<<<8192, blk, 0, stream>>>(xc, xn, ln3_g, ln3_b);
  ffn_k<<<512, blk, 0, stream>>>(xn, W1t, W2t, ffn_b1, ffn_b2, xc, out);
}

// Round 3
// 531.722 us; speedup vs baseline: 2.1983x; 2.1983x over previous
//
#include <hip/hip_runtime.h>
#include <hip/hip_bf16.h>

// DecoderBlock: B=128, T=S=256, C=384, H=6, D=64. fp32 in/out, bf16 MFMA compute.
#define BB 128
#define TT 256
#define CC 384
#define HH 6
#define DD 64
#define NTOK 32768  // B*T

typedef __attribute__((ext_vector_type(8))) short short8;
typedef __attribute__((ext_vector_type(4))) float f32x4;

__device__ __forceinline__ unsigned short f2bf(float f) {
  union { float f; unsigned int u; } v; v.f = f;
  unsigned int r = v.u + 0x7fff + ((v.u >> 16) & 1);  // RNE
  return (unsigned short)(r >> 16);
}

__device__ __forceinline__ void glds16(const void* g, void* l) {
  __builtin_amdgcn_global_load_lds((const __attribute__((address_space(1))) void*)g,
                                   (__attribute__((address_space(3))) void*)l, 16, 0, 0);
}

// ---------------- merged weight packing ----------------
// headstack: dst[(h*64+d)*384 + c] = src[h*24576 + c*64 + d]
// transpose: dst[n*Cdim + c] = src[c*Ndim + n]
__global__ __launch_bounds__(256) void pack_all_k(
    const float* __restrict__ wq1, const float* __restrict__ wk1, const float* __restrict__ wv1,
    const float* __restrict__ wq2, const float* __restrict__ wk2, const float* __restrict__ wv2,
    const float* __restrict__ proj1_w, const float* __restrict__ proj2_w,
    const float* __restrict__ ffn_w1, const float* __restrict__ ffn_w2,
    unsigned short* __restrict__ W) {
  int idx = blockIdx.x * 256 + threadIdx.x;  // over 2359296
  if (idx < 589824) {  // wq1,wk1,wv1,wq2 headstack
    int sub = idx / 147456, r = idx - sub * 147456;
    const float* src = sub == 0 ? wq1 : sub == 1 ? wk1 : sub == 2 ? wv1 : wq2;
    unsigned short* dst = W + sub * 147456;
    int h = r / 24576, rem = r - h * 24576;
    int c = rem >> 6, d = rem & 63;
    dst[(h * 64 + d) * 384 + c] = f2bf(src[r]);
  } else if (idx < 884736) {  // wk2, wv2 headstack
    int t = idx - 589824;
    int sub = t / 147456, r = t - sub * 147456;
    const float* src = sub ? wv2 : wk2;
    unsigned short* dst = W + 589824 + sub * 147456;
    int h = r / 24576, rem = r - h * 24576;
    int c = rem >> 6, d = rem & 63;
    dst[(h * 64 + d) * 384 + c] = f2bf(src[r]);
  } else if (idx < 1179648) {  // proj1, proj2 transpose 384x384
    int t = idx - 884736;
    int sub = t / 147456, r = t - sub * 147456;
    const float* src = sub ? proj2_w : proj1_w;
    unsigned short* dst = W + 884736 + sub * 147456;
    int c = r / 384, n = r - c * 384;
    dst[n * 384 + c] = f2bf(src[r]);
  } else if (idx < 1769472) {  // ffn_w1 transpose 384x1536
    int r = idx - 1179648;
    int c = r / 1536, n = r - c * 1536;
    (W + 1179648)[n * 384 + c] = f2bf(ffn_w1[r]);
  } else {  // ffn_w2 transpose 1536x384
    int r = idx - 1769472;
    int c = r / 384, n = r - c * 384;
    (W + 1769472)[n * 1536 + c] = f2bf(ffn_w2[r]);
  }
}

// ---------------- layernorm (fp32 in -> bf16 out) ----------------
__global__ __launch_bounds__(256) void ln_k(const float* __restrict__ x,
                                            unsigned short* __restrict__ out,
                                            const float* __restrict__ gamma,
                                            const float* __restrict__ beta) {
  int row = blockIdx.x * 4 + (threadIdx.x >> 6);
  int lane = threadIdx.x & 63;
  const float* xr = x + (size_t)row * CC;
  float v[6];
  float s = 0.f;
#pragma unroll
  for (int j = 0; j < 6; ++j) { v[j] = xr[j * 64 + lane]; s += v[j]; }
#pragma unroll
  for (int m = 1; m < 64; m <<= 1) s += __shfl_xor(s, m);
  float mu = s * (1.0f / CC);
  float vs = 0.f;
#pragma unroll
  for (int j = 0; j < 6; ++j) { float d = v[j] - mu; vs += d * d; }
#pragma unroll
  for (int m = 1; m < 64; m <<= 1) vs += __shfl_xor(vs, m);
  float rs = rsqrtf(vs * (1.0f / CC) + 1e-5f);
  unsigned short* orow = out + (size_t)row * CC;
#pragma unroll
  for (int j = 0; j < 6; ++j) {
    int cidx = j * 64 + lane;
    orow[cidx] = f2bf((v[j] - mu) * rs * gamma[cidx] + beta[cidx]);
  }
}

// ---------------- GEMM: C(MxN) = A(MxK) * Bt(NxK)^T ----------------
// 128x128 tile, 4 waves. LDS: linear dest via global_load_lds, source pre-swizzled,
// reads XOR-swizzled (involution). XCD-aware bijective 1D grid swizzle.
// EPI 0: C=bf16 acc ; EPI 1: C=bf16 relu(acc+bias) ; EPI 2: C=fp32 res+acc+bias
template <int EPI, bool AF32>
__global__ __launch_bounds__(256) void gemm_k(const void* __restrict__ Ap, int lda,
                                              const unsigned short* __restrict__ Bt, int ldb,
                                              void* __restrict__ Cp, int ldc,
                                              const float* __restrict__ bias,
                                              const float* __restrict__ res, int ldres,
                                              int K, int nx) {
  __shared__ unsigned short sA[128 * 64];
  __shared__ unsigned short sB[128 * 64];
  const int tid = threadIdx.x;
  const int chunkg = gridDim.x >> 3;
  const int wg = blockIdx.x;
  const int lg = (wg & 7) * chunkg + (wg >> 3);
  const int bx = lg % nx, by = lg / nx;
  const int m0 = by * 128;
  const int n0 = bx * 128;
  const int wid = tid >> 6, lane = tid & 63;
  const int wr = wid >> 1, wc = wid & 1;
  const int g = lane >> 4, c = lane & 15;

  f32x4 acc[4][4] = {};

  for (int k0 = 0; k0 < K; k0 += 64) {
    if constexpr (!AF32) {
#pragma unroll
      for (int t = 0; t < 4; ++t) {
        int chunk = t * 256 + tid;
        int row = chunk >> 3, grp = chunk & 7;
        const unsigned short* Ab = (const unsigned short*)Ap;
        glds16(&Ab[(size_t)(m0 + row) * lda + k0 + ((grp ^ (row & 7)) << 3)], &sA[chunk * 8]);
      }
    } else {
#pragma unroll
      for (int t = 0; t < 4; ++t) {
        int chunk = t * 256 + tid;
        int row = chunk >> 3, grp = chunk & 7;
        int dst = row * 64 + ((grp ^ (row & 7)) << 3);
        const float* Af = (const float*)Ap + (size_t)(m0 + row) * lda + k0 + grp * 8;
        float4 f0 = *(const float4*)Af;
        float4 f1 = *(const float4*)(Af + 4);
        union { unsigned short h[8]; uint4 u; } t2;
        t2.h[0] = f2bf(f0.x); t2.h[1] = f2bf(f0.y); t2.h[2] = f2bf(f0.z); t2.h[3] = f2bf(f0.w);
        t2.h[4] = f2bf(f1.x); t2.h[5] = f2bf(f1.y); t2.h[6] = f2bf(f1.z); t2.h[7] = f2bf(f1.w);
        *(uint4*)&sA[dst] = t2.u;
      }
    }
#pragma unroll
    for (int t = 0; t < 4; ++t) {
      int chunk = t * 256 + tid;
      int row = chunk >> 3, grp = chunk & 7;
      glds16(&Bt[(size_t)(n0 + row) * ldb + k0 + ((grp ^ (row & 7)) << 3)], &sB[chunk * 8]);
    }
    __syncthreads();
#pragma unroll
    for (int kk = 0; kk < 2; ++kk) {
      short8 a[4], b[4];
#pragma unroll
      for (int mi = 0; mi < 4; ++mi) {
        int r = wr * 64 + mi * 16 + c;
        a[mi] = *(const short8*)&sA[r * 64 + (((kk * 4 + g) ^ (r & 7)) << 3)];
      }
#pragma unroll
      for (int ni = 0; ni < 4; ++ni) {
        int rb = wc * 64 + ni * 16 + c;
        b[ni] = *(const short8*)&sB[rb * 64 + (((kk * 4 + g) ^ (rb & 7)) << 3)];
      }
#pragma unroll
      for (int mi = 0; mi < 4; ++mi)
#pragma unroll
        for (int ni = 0; ni < 4; ++ni)
          acc[mi][ni] = __builtin_amdgcn_mfma_f32_16x16x32_bf16(a[mi], b[ni], acc[mi][ni], 0, 0, 0);
    }
    __syncthreads();
  }

#pragma unroll
  for (int mi = 0; mi < 4; ++mi) {
#pragma unroll
    for (int ni = 0; ni < 4; ++ni) {
#pragma unroll
      for (int i = 0; i < 4; ++i) {
        int row = m0 + wr * 64 + mi * 16 + g * 4 + i;
        int col = n0 + wc * 64 + ni * 16 + c;
        float v = acc[mi][ni][i];
        if (EPI == 0) {
          ((unsigned short*)Cp)[(size_t)row * ldc + col] = f2bf(v);
        } else if (EPI == 1) {
          v += bias[col];
          ((unsigned short*)Cp)[(size_t)row * ldc + col] = f2bf(fmaxf(v, 0.f));
        } else {
          v += bias[col] + res[(size_t)row * ldres + col];
          ((float*)Cp)[(size_t)row * ldc + col] = v;
        }
      }
    }
  }
}

// ---------------- attention (per (b,h) block) ----------------
// QKV: (B*T, 1152) bf16 — Q at col 0, K at 384, V at 768 (+h*64)
// Ks XOR-swizzled (16B groups), Vt padded stride 258, Ps padded stride 260.
__global__ __launch_bounds__(256) void attn_k(const unsigned short* __restrict__ QKV,
                                              unsigned short* __restrict__ O,
                                              int causal) {
  __shared__ unsigned short Ks[256 * 64];      // [s][d] swizzled
  __shared__ unsigned short Vt[64 * 258];      // [d][s] padded
  __shared__ unsigned short Ps[4][16 * 260];   // per-wave [16 q][256 s] padded
  const int bh = blockIdx.x;
  const int b = bh / HH, hh = bh - b * HH;
  const int tid = threadIdx.x, wid = tid >> 6, lane = tid & 63;
  const int g = lane >> 4, c = lane & 15;
  const unsigned short* base = QKV + (size_t)b * TT * 1152;

#pragma unroll
  for (int t = 0; t < 8; ++t) {
    int chunk = t * 256 + tid;        // 2048 chunks of 8 elems
    int s = chunk >> 3, grp = chunk & 7;
    *(uint4*)&Ks[s * 64 + ((grp ^ (s & 7)) << 3)] =
        *(const uint4*)&base[(size_t)s * 1152 + 384 + hh * 64 + grp * 8];
    union { unsigned short h[8]; uint4 u; } tv;
    tv.u = *(const uint4*)&base[(size_t)s * 1152 + 768 + hh * 64 + grp * 8];
#pragma unroll
    for (int j = 0; j < 8; ++j) Vt[(grp * 8 + j) * 258 + s] = tv.h[j];
  }
  __syncthreads();

  const float scale = 0.05103103630798287f;  // 384^-0.5
  unsigned short* Pw = &Ps[wid][0];

  for (int qb = 0; qb < 4; ++qb) {
    const int qr0 = wid * 64 + qb * 16;
    short8 aq[2];
#pragma unroll
    for (int kk = 0; kk < 2; ++kk)
      aq[kk] = *(const short8*)&QKV[(size_t)(b * TT + qr0 + c) * 1152 + hh * 64 + kk * 32 + g * 8];

    f32x4 sacc[16];
#pragma unroll
    for (int sj = 0; sj < 16; ++sj) {
      int rk = sj * 16 + c;
      f32x4 z = {};
      z = __builtin_amdgcn_mfma_f32_16x16x32_bf16(
          aq[0], *(const short8*)&Ks[rk * 64 + ((g ^ (rk & 7)) << 3)], z, 0, 0, 0);
      z = __builtin_amdgcn_mfma_f32_16x16x32_bf16(
          aq[1], *(const short8*)&Ks[rk * 64 + (((4 + g) ^ (rk & 7)) << 3)], z, 0, 0, 0);
      sacc[sj] = z;
    }

#pragma unroll
    for (int i = 0; i < 4; ++i) {
      const int qr = qr0 + g * 4 + i;
      float mx = -1e30f;
#pragma unroll
      for (int sj = 0; sj < 16; ++sj) {
        int s = sj * 16 + c;
        float v = sacc[sj][i] * scale;
        if (causal && s > qr) v = -1e30f;
        sacc[sj][i] = v;
        mx = fmaxf(mx, v);
      }
#pragma unroll
      for (int m = 1; m < 16; m <<= 1) mx = fmaxf(mx, __shfl_xor(mx, m));
      float sum = 0.f;
#pragma unroll
      for (int sj = 0; sj < 16; ++sj) {
        float p = __expf(sacc[sj][i] - mx);
        sacc[sj][i] = p;
        sum += p;
      }
#pragma unroll
      for (int m = 1; m < 16; m <<= 1) sum += __shfl_xor(sum, m);
      float inv = 1.0f / sum;
#pragma unroll
      for (int sj = 0; sj < 16; ++sj)
        Pw[(g * 4 + i) * 260 + sj * 16 + c] = f2bf(sacc[sj][i] * inv);
    }

    f32x4 oacc[4] = {};
#pragma unroll
    for (int sk = 0; sk < 8; ++sk) {
      short8 ap = *(const short8*)&Pw[c * 260 + sk * 32 + g * 8];
#pragma unroll
      for (int dj = 0; dj < 4; ++dj) {
        short8 bv = *(const short8*)&Vt[(dj * 16 + c) * 258 + sk * 32 + g * 8];
        oacc[dj] = __builtin_amdgcn_mfma_f32_16x16x32_bf16(ap, bv, oacc[dj], 0, 0, 0);
      }
    }
#pragma unroll
    for (int dj = 0; dj < 4; ++dj)
#pragma unroll
      for (int i = 0; i < 4; ++i) {
        int qr = qr0 + g * 4 + i;
        O[(size_t)(b * TT + qr) * CC + hh * 64 + dj * 16 + c] = f2bf(oacc[dj][i]);
      }
  }
}

// ---------------- launcher ----------------
extern "C" void kernel_launch(void* const* d_in, const int* in_sizes, int n_in,
                              void* d_out, int out_size, void* d_ws, size_t ws_size,
                              hipStream_t stream) {
  const float* x = (const float*)d_in[0];
  const float* enc = (const float*)d_in[1];
  const float* wq1 = (const float*)d_in[2];
  const float* wk1 = (const float*)d_in[3];
  const float* wv1 = (const float*)d_in[4];
  const float* proj1_w = (const float*)d_in[5];
  const float* proj1_b = (const float*)d_in[6];
  const float* wq2 = (const float*)d_in[7];
  const float* wk2 = (const float*)d_in[8];
  const float* wv2 = (const float*)d_in[9];
  const float* proj2_w = (const float*)d_in[10];
  const float* proj2_b = (const float*)d_in[11];
  const float* ffn_w1 = (const float*)d_in[12];
  const float* ffn_b1 = (const float*)d_in[13];
  const float* ffn_w2 = (const float*)d_in[14];
  const float* ffn_b2 = (const float*)d_in[15];
  const float* ln1_g = (const float*)d_in[16];
  const float* ln1_b = (const float*)d_in[17];
  const float* ln2_g = (const float*)d_in[18];
  const float* ln2_b = (const float*)d_in[19];
  const float* ln3_g = (const float*)d_in[20];
  const float* ln3_b = (const float*)d_in[21];
  float* out = (float*)d_out;

  char* ws = (char*)d_ws;
  const size_t OFF_A = 0;           // x_cur fp32 (B*T,384)        50331648
  const size_t OFF_X = 50331648;    // xn bf16 (B*T,384)           25165824
  const size_t OFF_Q = 75497472;    // QKV bf16 (B*T,1152) / h1 bf16 (B*T,1536)
  const size_t OFF_O = 150994944;   // O bf16 (B*T,384)            25165824
  const size_t OFF_W = 176160768;   // packed weights bf16          4718592

  float* xc = (float*)(ws + OFF_A);
  unsigned short* xn = (unsigned short*)(ws + OFF_X);
  unsigned short* qkv = (unsigned short*)(ws + OFF_Q);
  unsigned short* h1 = (unsigned short*)(ws + OFF_Q);  // aliased; qkv/obuf dead by FFN
  unsigned short* obuf = (unsigned short*)(ws + OFF_O);
  unsigned short* W = (unsigned short*)(ws + OFF_W);

  unsigned short* Wqkv1t = W + 0;        // 1152x384
  unsigned short* Wq2t = W + 442368;     // 384x384
  unsigned short* Wkv2t = W + 589824;    // 768x384
  unsigned short* proj1t = W + 884736;   // 384x384
  unsigned short* proj2t = W + 1032192;  // 384x384
  unsigned short* W1t = W + 1179648;     // 1536x384
  unsigned short* W2t = W + 1769472;     // 384x1536

  // ---- pack all weights (one kernel) ----
  pack_all_k<<<9216, 256, 0, stream>>>(wq1, wk1, wv1, wq2, wk2, wv2,
                                       proj1_w, proj2_w, ffn_w1, ffn_w2, W);

  dim3 blk(256);
  // ---- layer 1: masked self-attention ----
  ln_k<<<8192, blk, 0, stream>>>(x, xn, ln1_g, ln1_b);
  gemm_k<0, false><<<2304, blk, 0, stream>>>(xn, 384, Wqkv1t, 384, qkv, 1152,
                                             nullptr, nullptr, 0, 384, 9);
  attn_k<<<768, blk, 0, stream>>>(qkv, obuf, 1);
  gemm_k<2, false><<<768, blk, 0, stream>>>(obuf, 384, proj1t, 384, xc, 384,
                                            proj1_b, x, 384, 384, 3);
  // ---- layer 2: cross-attention ----
  ln_k<<<8192, blk, 0, stream>>>(xc, xn, ln2_g, ln2_b);
  gemm_k<0, false><<<768, blk, 0, stream>>>(xn, 384, Wq2t, 384, qkv, 1152,
                                            nullptr, nullptr, 0, 384, 3);
  gemm_k<0, true><<<1536, blk, 0, stream>>>(enc, 384, Wkv2t, 384, qkv + 384, 1152,
                                            nullptr, nullptr, 0, 384, 6);
  attn_k<<<768, blk, 0, stream>>>(qkv, obuf, 0);
  gemm_k<2, false><<<768, blk, 0, stream>>>(obuf, 384, proj2t, 384, xc, 384,
                                            proj2_b, xc, 384, 384, 3);
  // ---- FFN: two proper GEMMs (fused ffn_k reverted — was latency-bound) ----
  ln_k<<<8192, blk, 0, stream>>>(xc, xn, ln3_g, ln3_b);
  gemm_k<1, false><<<3072, blk, 0, stream>>>(xn, 384, W1t, 384, h1, 1536,
                                             ffn_b1, nullptr, 0, 384, 12);
  gemm_k<2, false><<<768, blk, 0, stream>>>(h1, 1536, W2t, 1536, out, 384,
                                            ffn_b2, xc, 384, 1536, 3);
}

// Round 4
// 444.715 us; speedup vs baseline: 2.6284x; 1.1956x over previous
//
#include <hip/hip_runtime.h>
#include <hip/hip_bf16.h>

// DecoderBlock: B=128, T=S=256, C=384, H=6, D=64. fp32 in/out, bf16 MFMA compute.
#define BB 128
#define TT 256
#define CC 384
#define HH 6
#define DD 64
#define NTOK 32768  // B*T

typedef __attribute__((ext_vector_type(8))) short short8;
typedef __attribute__((ext_vector_type(4))) float f32x4;

__device__ __forceinline__ unsigned short f2bf(float f) {
  union { float f; unsigned int u; } v; v.f = f;
  unsigned int r = v.u + 0x7fff + ((v.u >> 16) & 1);  // RNE
  return (unsigned short)(r >> 16);
}

__device__ __forceinline__ void glds16(const void* g, void* l) {
  __builtin_amdgcn_global_load_lds((const __attribute__((address_space(1))) void*)g,
                                   (__attribute__((address_space(3))) void*)l, 16, 0, 0);
}

// ---------------- merged weight packing ----------------
__global__ __launch_bounds__(256) void pack_all_k(
    const float* __restrict__ wq1, const float* __restrict__ wk1, const float* __restrict__ wv1,
    const float* __restrict__ wq2, const float* __restrict__ wk2, const float* __restrict__ wv2,
    const float* __restrict__ proj1_w, const float* __restrict__ proj2_w,
    const float* __restrict__ ffn_w1, const float* __restrict__ ffn_w2,
    unsigned short* __restrict__ W) {
  int idx = blockIdx.x * 256 + threadIdx.x;  // over 2359296
  if (idx < 589824) {  // wq1,wk1,wv1,wq2 headstack
    int sub = idx / 147456, r = idx - sub * 147456;
    const float* src = sub == 0 ? wq1 : sub == 1 ? wk1 : sub == 2 ? wv1 : wq2;
    unsigned short* dst = W + sub * 147456;
    int h = r / 24576, rem = r - h * 24576;
    int c = rem >> 6, d = rem & 63;
    dst[(h * 64 + d) * 384 + c] = f2bf(src[r]);
  } else if (idx < 884736) {  // wk2, wv2 headstack
    int t = idx - 589824;
    int sub = t / 147456, r = t - sub * 147456;
    const float* src = sub ? wv2 : wk2;
    unsigned short* dst = W + 589824 + sub * 147456;
    int h = r / 24576, rem = r - h * 24576;
    int c = rem >> 6, d = rem & 63;
    dst[(h * 64 + d) * 384 + c] = f2bf(src[r]);
  } else if (idx < 1179648) {  // proj1, proj2 transpose 384x384
    int t = idx - 884736;
    int sub = t / 147456, r = t - sub * 147456;
    const float* src = sub ? proj2_w : proj1_w;
    unsigned short* dst = W + 884736 + sub * 147456;
    int c = r / 384, n = r - c * 384;
    dst[n * 384 + c] = f2bf(src[r]);
  } else if (idx < 1769472) {  // ffn_w1 transpose 384x1536
    int r = idx - 1179648;
    int c = r / 1536, n = r - c * 1536;
    (W + 1179648)[n * 384 + c] = f2bf(ffn_w1[r]);
  } else {  // ffn_w2 transpose 1536x384
    int r = idx - 1769472;
    int c = r / 384, n = r - c * 384;
    (W + 1769472)[n * 1536 + c] = f2bf(ffn_w2[r]);
  }
}

// ---------------- layernorm (fp32 in -> bf16 out) ----------------
__global__ __launch_bounds__(256) void ln_k(const float* __restrict__ x,
                                            unsigned short* __restrict__ out,
                                            const float* __restrict__ gamma,
                                            const float* __restrict__ beta) {
  int row = blockIdx.x * 4 + (threadIdx.x >> 6);
  int lane = threadIdx.x & 63;
  const float* xr = x + (size_t)row * CC;
  float v[6];
  float s = 0.f;
#pragma unroll
  for (int j = 0; j < 6; ++j) { v[j] = xr[j * 64 + lane]; s += v[j]; }
#pragma unroll
  for (int m = 1; m < 64; m <<= 1) s += __shfl_xor(s, m);
  float mu = s * (1.0f / CC);
  float vs = 0.f;
#pragma unroll
  for (int j = 0; j < 6; ++j) { float d = v[j] - mu; vs += d * d; }
#pragma unroll
  for (int m = 1; m < 64; m <<= 1) vs += __shfl_xor(vs, m);
  float rs = rsqrtf(vs * (1.0f / CC) + 1e-5f);
  unsigned short* orow = out + (size_t)row * CC;
#pragma unroll
  for (int j = 0; j < 6; ++j) {
    int cidx = j * 64 + lane;
    orow[cidx] = f2bf((v[j] - mu) * rs * gamma[cidx] + beta[cidx]);
  }
}

// ---------------- GEMM: C(MxN) = A(MxK) * Bt(NxK)^T ----------------
// 128x128 tile, 4 waves. LDS: linear dest via global_load_lds, source pre-swizzled,
// reads XOR-swizzled (involution). XCD-aware bijective 1D grid swizzle.
// EPI 0: C=bf16 acc ; EPI 1: C=bf16 relu(acc+bias) ; EPI 2: C=fp32 res+acc+bias
template <int EPI, bool AF32>
__global__ __launch_bounds__(256) void gemm_k(const void* __restrict__ Ap, int lda,
                                              const unsigned short* __restrict__ Bt, int ldb,
                                              void* __restrict__ Cp, int ldc,
                                              const float* __restrict__ bias,
                                              const float* __restrict__ res, int ldres,
                                              int K, int nx) {
  __shared__ unsigned short sA[128 * 64];
  __shared__ unsigned short sB[128 * 64];
  const int tid = threadIdx.x;
  const int chunkg = gridDim.x >> 3;
  const int wg = blockIdx.x;
  const int lg = (wg & 7) * chunkg + (wg >> 3);
  const int bx = lg % nx, by = lg / nx;
  const int m0 = by * 128;
  const int n0 = bx * 128;
  const int wid = tid >> 6, lane = tid & 63;
  const int wr = wid >> 1, wc = wid & 1;
  const int g = lane >> 4, c = lane & 15;

  f32x4 acc[4][4] = {};

  for (int k0 = 0; k0 < K; k0 += 64) {
    if constexpr (!AF32) {
#pragma unroll
      for (int t = 0; t < 4; ++t) {
        int chunk = t * 256 + tid;
        int row = chunk >> 3, grp = chunk & 7;
        const unsigned short* Ab = (const unsigned short*)Ap;
        glds16(&Ab[(size_t)(m0 + row) * lda + k0 + ((grp ^ (row & 7)) << 3)], &sA[chunk * 8]);
      }
    } else {
#pragma unroll
      for (int t = 0; t < 4; ++t) {
        int chunk = t * 256 + tid;
        int row = chunk >> 3, grp = chunk & 7;
        int dst = row * 64 + ((grp ^ (row & 7)) << 3);
        const float* Af = (const float*)Ap + (size_t)(m0 + row) * lda + k0 + grp * 8;
        float4 f0 = *(const float4*)Af;
        float4 f1 = *(const float4*)(Af + 4);
        union { unsigned short h[8]; uint4 u; } t2;
        t2.h[0] = f2bf(f0.x); t2.h[1] = f2bf(f0.y); t2.h[2] = f2bf(f0.z); t2.h[3] = f2bf(f0.w);
        t2.h[4] = f2bf(f1.x); t2.h[5] = f2bf(f1.y); t2.h[6] = f2bf(f1.z); t2.h[7] = f2bf(f1.w);
        *(uint4*)&sA[dst] = t2.u;
      }
    }
#pragma unroll
    for (int t = 0; t < 4; ++t) {
      int chunk = t * 256 + tid;
      int row = chunk >> 3, grp = chunk & 7;
      glds16(&Bt[(size_t)(n0 + row) * ldb + k0 + ((grp ^ (row & 7)) << 3)], &sB[chunk * 8]);
    }
    __syncthreads();
#pragma unroll
    for (int kk = 0; kk < 2; ++kk) {
      short8 a[4], b[4];
#pragma unroll
      for (int mi = 0; mi < 4; ++mi) {
        int r = wr * 64 + mi * 16 + c;
        a[mi] = *(const short8*)&sA[r * 64 + (((kk * 4 + g) ^ (r & 7)) << 3)];
      }
#pragma unroll
      for (int ni = 0; ni < 4; ++ni) {
        int rb = wc * 64 + ni * 16 + c;
        b[ni] = *(const short8*)&sB[rb * 64 + (((kk * 4 + g) ^ (rb & 7)) << 3)];
      }
#pragma unroll
      for (int mi = 0; mi < 4; ++mi)
#pragma unroll
        for (int ni = 0; ni < 4; ++ni)
          acc[mi][ni] = __builtin_amdgcn_mfma_f32_16x16x32_bf16(a[mi], b[ni], acc[mi][ni], 0, 0, 0);
    }
    __syncthreads();
  }

#pragma unroll
  for (int mi = 0; mi < 4; ++mi) {
#pragma unroll
    for (int ni = 0; ni < 4; ++ni) {
#pragma unroll
      for (int i = 0; i < 4; ++i) {
        int row = m0 + wr * 64 + mi * 16 + g * 4 + i;
        int col = n0 + wc * 64 + ni * 16 + c;
        float v = acc[mi][ni][i];
        if (EPI == 0) {
          ((unsigned short*)Cp)[(size_t)row * ldc + col] = f2bf(v);
        } else if (EPI == 1) {
          v += bias[col];
          ((unsigned short*)Cp)[(size_t)row * ldc + col] = f2bf(fmaxf(v, 0.f));
        } else {
          v += bias[col] + res[(size_t)row * ldres + col];
          ((float*)Cp)[(size_t)row * ldc + col] = v;
        }
      }
    }
  }
}

// ---------------- attention ----------------
// Grid: (b, h, half) = 1536 blocks x 512 threads (8 waves). Each wave owns 16 q-rows.
// LDS: Ks 32KB (XOR-swz) + Vt 32KB (rotate+XOR swz, conflict-free scatter) +
//      Ps 8x[16][40] streamed P chunks (10KB) = 74KB -> 2 blocks/CU.
// Vt swizzle: elem(d, s) = d*256 + ((((s>>3)+(d>>3))&31) ^ (d&7))*8 + (s&7)
__device__ __forceinline__ int vt_off(int d, int sgrp) {
  return d * 256 + ((((sgrp + (d >> 3)) & 31) ^ (d & 7)) << 3);
}

template <bool CAUSAL>
__global__ __launch_bounds__(512, 2) void attn_k(const unsigned short* __restrict__ QKV,
                                                 unsigned short* __restrict__ O) {
  __shared__ unsigned short Ks[256 * 64];
  __shared__ unsigned short Vt[64 * 256];
  __shared__ unsigned short Ps[8][16 * 40];
  const int bh = blockIdx.x >> 1;
  const int half = blockIdx.x & 1;
  const int b = bh / HH, hh = bh - b * HH;
  const int tid = threadIdx.x, wid = tid >> 6, lane = tid & 63;
  const int g = lane >> 4, c = lane & 15;
  const unsigned short* base = QKV + (size_t)b * TT * 1152;

#pragma unroll
  for (int t = 0; t < 4; ++t) {
    int chunk = t * 512 + tid;  // 2048 chunks of 8 elems
    int s = chunk >> 3, grp = chunk & 7;
    *(uint4*)&Ks[s * 64 + ((grp ^ (s & 7)) << 3)] =
        *(const uint4*)&base[(size_t)s * 1152 + 384 + hh * 64 + grp * 8];
    union { unsigned short h[8]; uint4 u; } tv;
    tv.u = *(const uint4*)&base[(size_t)s * 1152 + 768 + hh * 64 + grp * 8];
#pragma unroll
    for (int j = 0; j < 8; ++j) Vt[vt_off(grp * 8 + j, s >> 3) + (s & 7)] = tv.h[j];
  }
  __syncthreads();

  const float scale = 0.05103103630798287f;  // 384^-0.5
  unsigned short* Pw = &Ps[wid][0];
  const int qr0 = half * 128 + wid * 16;

  short8 aq[2];
#pragma unroll
  for (int kk = 0; kk < 2; ++kk)
    aq[kk] = *(const short8*)&QKV[(size_t)(b * TT + qr0 + c) * 1152 + hh * 64 + kk * 32 + g * 8];

  f32x4 sacc[16] = {};
#pragma unroll
  for (int sj = 0; sj < 16; ++sj) {
    if (!CAUSAL || sj * 16 <= qr0) {
      int rk = sj * 16 + c;
      f32x4 z = sacc[sj];
      z = __builtin_amdgcn_mfma_f32_16x16x32_bf16(
          aq[0], *(const short8*)&Ks[rk * 64 + ((g ^ (rk & 7)) << 3)], z, 0, 0, 0);
      z = __builtin_amdgcn_mfma_f32_16x16x32_bf16(
          aq[1], *(const short8*)&Ks[rk * 64 + (((4 + g) ^ (rk & 7)) << 3)], z, 0, 0, 0);
      sacc[sj] = z;
    }
  }

  float inv[4];
#pragma unroll
  for (int i = 0; i < 4; ++i) {
    const int qr = qr0 + g * 4 + i;
    float mx = -1e30f;
#pragma unroll
    for (int sj = 0; sj < 16; ++sj) {
      if (!CAUSAL || sj * 16 <= qr0) {
        int s = sj * 16 + c;
        float v = sacc[sj][i] * scale;
        if (CAUSAL && s > qr) v = -1e30f;
        sacc[sj][i] = v;
        mx = fmaxf(mx, v);
      }
    }
#pragma unroll
    for (int m = 1; m < 16; m <<= 1) mx = fmaxf(mx, __shfl_xor(mx, m));
    float sum = 0.f;
#pragma unroll
    for (int sj = 0; sj < 16; ++sj) {
      if (!CAUSAL || sj * 16 <= qr0) {
        float p = __expf(sacc[sj][i] - mx);
        sacc[sj][i] = p;  // unnormalized; 1/sum applied at O-write
        sum += p;
      }
    }
#pragma unroll
    for (int m = 1; m < 16; m <<= 1) sum += __shfl_xor(sum, m);
    inv[i] = 1.0f / sum;
  }

  f32x4 oacc[4] = {};
#pragma unroll
  for (int sk = 0; sk < 8; ++sk) {
    if (!CAUSAL || sk * 32 <= qr0) {
      // stream P chunk [16 q][32 s] into per-wave LDS (rows beyond causal limit are 0)
#pragma unroll
      for (int half_sj = 0; half_sj < 2; ++half_sj) {
        int sj = sk * 2 + half_sj;
#pragma unroll
        for (int i = 0; i < 4; ++i)
          Pw[(g * 4 + i) * 40 + half_sj * 16 + c] = f2bf(sacc[sj][i]);
      }
      short8 ap = *(const short8*)&Pw[c * 40 + g * 8];
#pragma unroll
      for (int dj = 0; dj < 4; ++dj) {
        short8 bv = *(const short8*)&Vt[vt_off(dj * 16 + c, sk * 4 + g)];
        oacc[dj] = __builtin_amdgcn_mfma_f32_16x16x32_bf16(ap, bv, oacc[dj], 0, 0, 0);
      }
    }
  }

#pragma unroll
  for (int dj = 0; dj < 4; ++dj)
#pragma unroll
    for (int i = 0; i < 4; ++i) {
      int qr = qr0 + g * 4 + i;
      O[(size_t)(b * TT + qr) * CC + hh * 64 + dj * 16 + c] = f2bf(oacc[dj][i] * inv[i]);
    }
}

// ---------------- launcher ----------------
extern "C" void kernel_launch(void* const* d_in, const int* in_sizes, int n_in,
                              void* d_out, int out_size, void* d_ws, size_t ws_size,
                              hipStream_t stream) {
  const float* x = (const float*)d_in[0];
  const float* enc = (const float*)d_in[1];
  const float* wq1 = (const float*)d_in[2];
  const float* wk1 = (const float*)d_in[3];
  const float* wv1 = (const float*)d_in[4];
  const float* proj1_w = (const float*)d_in[5];
  const float* proj1_b = (const float*)d_in[6];
  const float* wq2 = (const float*)d_in[7];
  const float* wk2 = (const float*)d_in[8];
  const float* wv2 = (const float*)d_in[9];
  const float* proj2_w = (const float*)d_in[10];
  const float* proj2_b = (const float*)d_in[11];
  const float* ffn_w1 = (const float*)d_in[12];
  const float* ffn_b1 = (const float*)d_in[13];
  const float* ffn_w2 = (const float*)d_in[14];
  const float* ffn_b2 = (const float*)d_in[15];
  const float* ln1_g = (const float*)d_in[16];
  const float* ln1_b = (const float*)d_in[17];
  const float* ln2_g = (const float*)d_in[18];
  const float* ln2_b = (const float*)d_in[19];
  const float* ln3_g = (const float*)d_in[20];
  const float* ln3_b = (const float*)d_in[21];
  float* out = (float*)d_out;

  char* ws = (char*)d_ws;
  const size_t OFF_A = 0;           // x_cur fp32 (B*T,384)        50331648
  const size_t OFF_X = 50331648;    // xn bf16 (B*T,384)           25165824
  const size_t OFF_Q = 75497472;    // QKV bf16 (B*T,1152) / h1 bf16 (B*T,1536)
  const size_t OFF_O = 150994944;   // O bf16 (B*T,384)            25165824
  const size_t OFF_W = 176160768;   // packed weights bf16          4718592

  float* xc = (float*)(ws + OFF_A);
  unsigned short* xn = (unsigned short*)(ws + OFF_X);
  unsigned short* qkv = (unsigned short*)(ws + OFF_Q);
  unsigned short* h1 = (unsigned short*)(ws + OFF_Q);  // aliased; qkv/obuf dead by FFN
  unsigned short* obuf = (unsigned short*)(ws + OFF_O);
  unsigned short* W = (unsigned short*)(ws + OFF_W);

  unsigned short* Wqkv1t = W + 0;        // 1152x384
  unsigned short* Wq2t = W + 442368;     // 384x384
  unsigned short* Wkv2t = W + 589824;    // 768x384
  unsigned short* proj1t = W + 884736;   // 384x384
  unsigned short* proj2t = W + 1032192;  // 384x384
  unsigned short* W1t = W + 1179648;     // 1536x384
  unsigned short* W2t = W + 1769472;     // 384x1536

  // ---- pack all weights (one kernel) ----
  pack_all_k<<<9216, 256, 0, stream>>>(wq1, wk1, wv1, wq2, wk2, wv2,
                                       proj1_w, proj2_w, ffn_w1, ffn_w2, W);

  dim3 blk(256);
  // ---- layer 1: masked self-attention ----
  ln_k<<<8192, blk, 0, stream>>>(x, xn, ln1_g, ln1_b);
  gemm_k<0, false><<<2304, blk, 0, stream>>>(xn, 384, Wqkv1t, 384, qkv, 1152,
                                             nullptr, nullptr, 0, 384, 9);
  attn_k<true><<<1536, 512, 0, stream>>>(qkv, obuf);
  gemm_k<2, false><<<768, blk, 0, stream>>>(obuf, 384, proj1t, 384, xc, 384,
                                            proj1_b, x, 384, 384, 3);
  // ---- layer 2: cross-attention ----
  ln_k<<<8192, blk, 0, stream>>>(xc, xn, ln2_g, ln2_b);
  gemm_k<0, false><<<768, blk, 0, stream>>>(xn, 384, Wq2t, 384, qkv, 1152,
                                            nullptr, nullptr, 0, 384, 3);
  gemm_k<0, true><<<1536, blk, 0, stream>>>(enc, 384, Wkv2t, 384, qkv + 384, 1152,
                                            nullptr, nullptr, 0, 384, 6);
  attn_k<false><<<1536, 512, 0, stream>>>(qkv, obuf);
  gemm_k<2, false><<<768, blk, 0, stream>>>(obuf, 384, proj2t, 384, xc, 384,
                                            proj2_b, xc, 384, 384, 3);
  // ---- FFN ----
  ln_k<<<8192, blk, 0, stream>>>(xc, xn, ln3_g, ln3_b);
  gemm_k<1, false><<<3072, blk, 0, stream>>>(xn, 384, W1t, 384, h1, 1536,
                                             ffn_b1, nullptr, 0, 384, 12);
  gemm_k<2, false><<<768, blk, 0, stream>>>(h1, 1536, W2t, 1536, out, 384,
                                            ffn_b2, xc, 384, 1536, 3);
}